// Round 6
// baseline (143.211 us; speedup 1.0000x reference)
//
#include <hip/hip_runtime.h>

#define T_LEN 16384
#define VAR_EPS 1e-5f

typedef float v4 __attribute__((ext_vector_type(4)));

typedef __attribute__((address_space(1))) const void GV;  // global
typedef __attribute__((address_space(3))) void       LV;  // LDS
typedef __attribute__((address_space(3))) float      LF;

// ---------------------------------------------------------------------------
// Stage 1: one block per row, 256 threads = 4 waves. Wave w owns floats
// [w*4096, (w+1)*4096) of both streams. Data is staged global->LDS via the
// global_load_lds DMA path (no VGPR writeback): chunks of 512 floats/stream
// (4 x 1024B DMA instrs), quad-buffered, 3 chunks (12 instrs, 12 KB) in
// flight steady-state with counted vmcnt(8) waits -- the pipeline never
// drains. ds_read_b128 + lgkmcnt(0) inside one asm block (rule #18), then
// VALU accumulate. Tests whether the LDS-DMA path's outstanding-request
// tracking is separate from the vector-return pool that caps R0-R5 at
// ~3.6 TB/s.
// LDS: 4 waves x 4 slots x 4 KB = 64 KB (2 blocks/CU).
// ---------------------------------------------------------------------------

#define ACC(P,Q)                                              \
    sp  += (P.x + P.y) + (P.z + P.w);                         \
    st  += (Q.x + Q.y) + (Q.z + Q.w);                         \
    spp += P.x*P.x + P.y*P.y + P.z*P.z + P.w*P.w;             \
    stt += Q.x*Q.x + Q.y*Q.y + Q.z*Q.z + Q.w*Q.w;             \
    spt += P.x*Q.x + P.y*Q.y + P.z*Q.z + P.w*Q.w;

__global__ __launch_bounds__(256) void pearson_row_kernel(
    const float* __restrict__ pred, const float* __restrict__ target,
    float* __restrict__ moments)
{
    __shared__ float lds[4][4][1024];   // [wave][slot][512 p | 512 t] = 64 KB

    const int row  = blockIdx.x;
    const int tid  = threadIdx.x;
    const int wid  = tid >> 6;
    const int lane = tid & 63;

    const float* pw = pred   + (size_t)row * T_LEN + wid * 4096;
    const float* tw = target + (size_t)row * T_LEN + wid * 4096;

    // Per-instr: 64 lanes x 16 B = 1024 B staged at lds_base + lane*16.
    // Chunk c: 512 floats of p -> slot floats [0,512), 512 of t -> [512,1024).
#define STAGE(c) do {                                                         \
    const int s_ = (c) & 3;                                                   \
    __builtin_amdgcn_global_load_lds((GV*)(pw + (c)*512       + lane*4),      \
                                     (LV*)&lds[wid][s_][0],   16, 0, 0);      \
    __builtin_amdgcn_global_load_lds((GV*)(pw + (c)*512 + 256 + lane*4),      \
                                     (LV*)&lds[wid][s_][256], 16, 0, 0);      \
    __builtin_amdgcn_global_load_lds((GV*)(tw + (c)*512       + lane*4),      \
                                     (LV*)&lds[wid][s_][512], 16, 0, 0);      \
    __builtin_amdgcn_global_load_lds((GV*)(tw + (c)*512 + 256 + lane*4),      \
                                     (LV*)&lds[wid][s_][768], 16, 0, 0);      \
  } while (0)

    // LDS byte address of this lane's 32-B p-slice within slot 0.
    const unsigned lane_base =
        (unsigned)(size_t)((LF*)&lds[wid][0][0]) + (unsigned)lane * 32u;

    float sp = 0.f, st = 0.f, spp = 0.f, stt = 0.f, spt = 0.f;

    // Prolog: 3 chunks (12 DMA instrs, 12 KB/wave) in flight.
    STAGE(0); STAGE(1); STAGE(2);

    #pragma unroll
    for (int c = 0; c < 8; ++c) {
        // Wait for chunk c only: leave the 2 younger chunks in flight.
        if      (c <= 5) asm volatile("s_waitcnt vmcnt(8)" ::: "memory");
        else if (c == 6) asm volatile("s_waitcnt vmcnt(4)" ::: "memory");
        else             asm volatile("s_waitcnt vmcnt(0)" ::: "memory");
        __builtin_amdgcn_sched_barrier(0);

        const unsigned a = lane_base + (unsigned)((c & 3) * 4096);
        v4 P0, P1, Q0, Q1;
        asm volatile(
            "ds_read_b128 %0, %4\n\t"
            "ds_read_b128 %1, %4 offset:16\n\t"
            "ds_read_b128 %2, %4 offset:2048\n\t"
            "ds_read_b128 %3, %4 offset:2064\n\t"
            "s_waitcnt lgkmcnt(0)"
            : "=&v"(P0), "=&v"(P1), "=&v"(Q0), "=&v"(Q1)
            : "v"(a) : "memory");

        ACC(P0, Q0);
        ACC(P1, Q1);

        if (c < 5) STAGE(c + 3);   // refill: slot (c+3)&3 was freed at c-1
    }
#undef STAGE

    // 64-lane wave reduction (5 moments).
    #pragma unroll
    for (int off = 32; off > 0; off >>= 1) {
        sp  += __shfl_down(sp,  off);
        st  += __shfl_down(st,  off);
        spp += __shfl_down(spp, off);
        stt += __shfl_down(stt, off);
        spt += __shfl_down(spt, off);
    }

    // Cross-wave combine. Reuse staging LDS (all reads drained above);
    // barrier first so no wave still owns its region.
    __syncthreads();
    float* wsf = (float*)&lds[0][0][0];
    if ((tid & 63) == 0) {
        wsf[wid * 8 + 0] = sp;  wsf[wid * 8 + 1] = st;
        wsf[wid * 8 + 2] = spp; wsf[wid * 8 + 3] = stt;
        wsf[wid * 8 + 4] = spt;
    }
    __syncthreads();

    if (tid == 0) {
        float* m = moments + (size_t)row * 8;
        m[0] = wsf[0] + wsf[8]  + wsf[16] + wsf[24];
        m[1] = wsf[1] + wsf[9]  + wsf[17] + wsf[25];
        m[2] = wsf[2] + wsf[10] + wsf[18] + wsf[26];
        m[3] = wsf[3] + wsf[11] + wsf[19] + wsf[27];
        m[4] = wsf[4] + wsf[12] + wsf[20] + wsf[28];
    }
}

// ---------------------------------------------------------------------------
// Stage 2: one block, 1024 threads -> one row each; per-row loss, then mean.
// ---------------------------------------------------------------------------
__global__ __launch_bounds__(1024) void pearson_final_kernel(
    const float* __restrict__ moments, float* __restrict__ out, int B)
{
    const int tid = threadIdx.x;
    float loss_sum = 0.f;

    for (int r = tid; r < B; r += 1024) {
        const float* m = moments + (size_t)r * 8;
        float S_p  = m[0];
        float S_t  = m[1];
        float S_pp = m[2];
        float S_tt = m[3];
        float S_pt = m[4];

        const float T   = (float)T_LEN;
        const float inv = 1.0f / T;
        float cp2 = S_pp - S_p * S_p * inv;
        float ct2 = S_tt - S_t * S_t * inv;
        float num = S_pt - S_p * S_t * inv;

        float var_p = cp2 / (T - 1.0f);
        float var_t = ct2 / (T - 1.0f);
        float denom = sqrtf(cp2 * ct2);
        float safe  = (denom > 0.0f) ? denom : 1.0f;
        float corr  = num / safe;
        bool valid = (var_p > VAR_EPS) && (var_t > VAR_EPS) &&
                     (denom > 0.0f) && !isnan(corr);
        loss_sum += valid ? (1.0f - corr) : 1.0f;
    }

    #pragma unroll
    for (int off = 32; off > 0; off >>= 1)
        loss_sum += __shfl_down(loss_sum, off);

    __shared__ float ws[16];
    if ((tid & 63) == 0) ws[tid >> 6] = loss_sum;
    __syncthreads();

    if (tid == 0) {
        float tot = 0.f;
        #pragma unroll
        for (int w = 0; w < 16; ++w) tot += ws[w];
        out[0] = tot / (float)B;
    }
}

extern "C" void kernel_launch(void* const* d_in, const int* in_sizes, int n_in,
                              void* d_out, int out_size, void* d_ws, size_t ws_size,
                              hipStream_t stream) {
    const float* pred   = (const float*)d_in[0];
    const float* target = (const float*)d_in[1];
    float* out     = (float*)d_out;
    float* moments = (float*)d_ws;              // B*8 floats, fully overwritten

    const int B = in_sizes[0] / T_LEN;

    pearson_row_kernel<<<B, 256, 0, stream>>>(pred, target, moments);
    pearson_final_kernel<<<1, 1024, 0, stream>>>(moments, out, B);
}